// Round 9
// baseline (127.883 us; speedup 1.0000x reference)
//
#include <hip/hip_runtime.h>
#include <hip/hip_bf16.h>
#include <stdint.h>

// Problem geometry
#define B_   64
#define C_   512
#define L_   784      // 28*28
#define LP   800      // padded row length (25 * 32), pad is zero-filled
#define TILE 128
#define KSTEPS 25
#define NPAIR 10      // unordered tile pairs (i<=j) of 4 row-tiles
#define NXCD 8
#define NROWS 65536   // 2 * B_ * C_

#define AS1 __attribute__((address_space(1)))
#define AS3 __attribute__((address_space(3)))

typedef __attribute__((ext_vector_type(8))) __bf16 bf16x8;
typedef __attribute__((ext_vector_type(4))) float  f32x4;

#define WAITV4  asm volatile("s_waitcnt vmcnt(4)"  ::: "memory")
#define WAITV0  asm volatile("s_waitcnt vmcnt(0)"  ::: "memory")
#define LGKM0   asm volatile("s_waitcnt lgkmcnt(0)" ::: "memory")
#define SBAR    __builtin_amdgcn_s_barrier()
#define SCHED0  __builtin_amdgcn_sched_barrier(0)
#define GLD16(SRC, DST) __builtin_amdgcn_global_load_lds((AS1 const void*)(SRC), (AS3 void*)(DST), 16, 0, 0)

// ---------------------------------------------------------------------------
// round-to-nearest-even float -> bf16 bits (data has no NaN/Inf)
__device__ inline unsigned short f2bf(float x) {
    union { float f; uint32_t u; } a; a.f = x;
    uint32_t u = a.u;
    return (unsigned short)((u + 0x7fffu + ((u >> 16) & 1u)) >> 16);
}

// ---------------------------------------------------------------------------
__global__ void init_kernel(float* partials) {
    if (threadIdx.x < 16) partials[threadIdx.x] = 0.0f;
}

// ---------------------------------------------------------------------------
// Pass 1 (v2): L2-normalize rows, fp32 -> bf16 padded to LP=800.
// Grid-stride over ROW PAIRS: each wave holds 2 rows in flight (8 concurrent
// 16B loads, two interleaved shuffle-reductions) -> 2x ILP vs one-row waves;
// 2048 persistent blocks instead of 8192 short-lived ones.
__global__ __launch_bounds__(256) void normalize_kernel(
    const float* __restrict__ fs, const float* __restrict__ ft,
    unsigned short* __restrict__ outT, unsigned short* __restrict__ outS)
{
    int wave0  = blockIdx.x * 4 + (threadIdx.x >> 6);
    int lane   = threadIdx.x & 63;
    int nwaves = gridDim.x * 4;

    for (int rp = wave0; rp < NROWS / 2; rp += nwaves) {
        int rowA = rp * 2;                 // even; rowB = rowA+1 in same matrix
        int mat  = rowA >> 15;             // 0 -> t, 1 -> s (32768 rows each)
        int ra   = rowA & 32767;

        const float* srcA = (mat == 0 ? ft : fs) + (size_t)ra * L_;
        const float* srcB = srcA + L_;
        unsigned short* dstA = (mat == 0 ? outT : outS) + (size_t)ra * LP;
        unsigned short* dstB = dstA + LP;

        float4 va[4], vb[4];
        float ssa = 0.0f, ssb = 0.0f;
#pragma unroll
        for (int it = 0; it < 3; ++it) {   // chunks 0..191: all lanes active
            int c = it * 64 + lane;
            va[it] = reinterpret_cast<const float4*>(srcA)[c];
            vb[it] = reinterpret_cast<const float4*>(srcB)[c];
        }
        if (lane < 4) {                    // chunks 192..195
            va[3] = reinterpret_cast<const float4*>(srcA)[192 + lane];
            vb[3] = reinterpret_cast<const float4*>(srcB)[192 + lane];
        } else {
            va[3] = make_float4(0.f, 0.f, 0.f, 0.f);
            vb[3] = make_float4(0.f, 0.f, 0.f, 0.f);
        }
#pragma unroll
        for (int it = 0; it < 4; ++it) {
            ssa += va[it].x * va[it].x + va[it].y * va[it].y
                 + va[it].z * va[it].z + va[it].w * va[it].w;
            ssb += vb[it].x * vb[it].x + vb[it].y * vb[it].y
                 + vb[it].z * vb[it].z + vb[it].w * vb[it].w;
        }
#pragma unroll
        for (int m = 32; m >= 1; m >>= 1) {
            ssa += __shfl_xor(ssa, m, 64);
            ssb += __shfl_xor(ssb, m, 64);
        }
        float rna = 1.0f / fmaxf(sqrtf(ssa), 1e-12f);
        float rnb = 1.0f / fmaxf(sqrtf(ssb), 1e-12f);

#pragma unroll
        for (int it = 0; it < 3; ++it) {
            int c = it * 64 + lane;
            ushort4 oa, ob;
            oa.x = f2bf(va[it].x * rna); oa.y = f2bf(va[it].y * rna);
            oa.z = f2bf(va[it].z * rna); oa.w = f2bf(va[it].w * rna);
            ob.x = f2bf(vb[it].x * rnb); ob.y = f2bf(vb[it].y * rnb);
            ob.z = f2bf(vb[it].z * rnb); ob.w = f2bf(vb[it].w * rnb);
            *reinterpret_cast<ushort4*>(dstA + (size_t)c * 4) = oa;
            *reinterpret_cast<ushort4*>(dstB + (size_t)c * 4) = ob;
        }
        if (lane < 8) {                    // chunks 192..199 (data + zero pad)
            ushort4 oa = make_ushort4(0, 0, 0, 0), ob = oa;
            if (lane < 4) {
                oa.x = f2bf(va[3].x * rna); oa.y = f2bf(va[3].y * rna);
                oa.z = f2bf(va[3].z * rna); oa.w = f2bf(va[3].w * rna);
                ob.x = f2bf(vb[3].x * rnb); ob.y = f2bf(vb[3].y * rnb);
                ob.z = f2bf(vb[3].z * rnb); ob.w = f2bf(vb[3].w * rnb);
            }
            *reinterpret_cast<ushort4*>(dstA + (size_t)(192 + lane) * 4) = oa;
            *reinterpret_cast<ushort4*>(dstB + (size_t)(192 + lane) * 4) = ob;
        }
    }
}

// ---------------------------------------------------------------------------
// Pass 2 (fused, 4-phase schedule): UNCHANGED from R8 (clean A/B vs normalize).
// One block per (batch, pair{i<=j}), full K. Stages panels T_i,T_j,S_i,S_j
// (8KB each) once per K-step; computes all four 128x128 products tt,st,ts,ss.
// 8 waves; wave w owns rows (w>>2)*64, cols (w&3)*32: 12 LDS frags -> 32 MFMA
// per step, 4 phases of {ds_read || 1 stage-GLD -> bar -> lgkm0 -> 8 MFMA ->
// bar}. Counted vmcnt(4) once per K-step; setprio; both-sides XOR swizzle;
// XCD block swizzle.
__global__ __launch_bounds__(512, 1) void gram_kernel(
    const unsigned short* __restrict__ Tn,
    const unsigned short* __restrict__ Sn,
    float* __restrict__ partials)
{
    // T1: bijective XCD chunk swizzle (640 = 8 XCDs x 80; 8 batches/XCD)
    int blk = (blockIdx.x % NXCD) * (B_ * NPAIR / NXCD) + blockIdx.x / NXCD;
    int b   = blk / NPAIR;
    int t   = blk % NPAIR;

    int i, j;
    if      (t < 4) { i = 0; j = t;     }
    else if (t < 7) { i = 1; j = t - 3; }
    else if (t < 9) { i = 2; j = t - 5; }
    else            { i = 3; j = 3;     }

    float wsym   = (i == j) ? 1.0f : 2.0f;
    float wcross = (i == j) ? 0.5f : 1.0f;

    const unsigned short* Ti = Tn + (size_t)b * C_ * LP + (size_t)i * TILE * LP;
    const unsigned short* Tj = Tn + (size_t)b * C_ * LP + (size_t)j * TILE * LP;
    const unsigned short* Si = Sn + (size_t)b * C_ * LP + (size_t)i * TILE * LP;
    const unsigned short* Sj = Sn + (size_t)b * C_ * LP + (size_t)j * TILE * LP;

    // 3 buffers x 32KB = 96KB; panel layout per buffer (shorts):
    // Ti@0, Tj@4096, Si@8192, Sj@12288
    __shared__ unsigned short lds[3 * 16384];
    __shared__ float red[8];

    int tid  = threadIdx.x;
    int wid  = tid >> 6;
    int lane = tid & 63;

    // staging addresses (T2 swizzle by pre-swizzled global source slot)
    int sr  = tid >> 2;                      // panel row 0..127
    int ssl = (tid & 3) ^ ((sr >> 1) & 3);   // swizzled 16B slot in row
    const size_t gOff = (size_t)sr * LP + ssl * 8;   // + k0 per step
    const int dOff = wid * 512;              // shorts; lane*16B implicit

    // fragment read addresses (swizzled read side, involution matches source)
    int rA = (wid >> 2) * 64 + (lane & 15);  // A-side panel row
    int rB = (wid & 3) * 32 + (lane & 15);   // B-side panel row
    int kb = (lane >> 4) * 16;               // 16B k-slot (bytes)
    int aByte = rA * 64 + (kb ^ (((rA >> 1) & 3) << 4));
    int bByte = rB * 64 + (kb ^ (((rB >> 1) & 3) << 4));

    f32x4 att[4][2] = {}, ast[4][2] = {}, ats[4][2] = {}, ass[4][2] = {};

    unsigned short* c0 = lds;
    unsigned short* c1 = lds + 16384;
    unsigned short* c2 = lds + 32768;

    // prologue: stage tiles 0,1 (8 GLD/thread outstanding)
    {
        GLD16(Ti + gOff, c0 + dOff);  GLD16(Tj + gOff, c0 + 4096 + dOff);
        GLD16(Si + gOff, c0 + 8192 + dOff);  GLD16(Sj + gOff, c0 + 12288 + dOff);
        GLD16(Ti + gOff + 32, c1 + dOff);  GLD16(Tj + gOff + 32, c1 + 4096 + dOff);
        GLD16(Si + gOff + 32, c1 + 8192 + dOff);  GLD16(Sj + gOff + 32, c1 + 12288 + dOff);
    }
    WAITV4;                 // tile 0 landed; tile 1's 4 loads in flight
    SBAR; SCHED0;

#define MFMA8(ACC, FA, FB)                                                             \
    _Pragma("unroll")                                                                  \
    for (int m = 0; m < 4; ++m)                                                        \
        _Pragma("unroll")                                                              \
        for (int n = 0; n < 2; ++n)                                                    \
            ACC[m][n] = __builtin_amdgcn_mfma_f32_16x16x32_bf16(FA[m], FB[n], ACC[m][n], 0, 0, 0);

#define KSTEP(BUF, NBUF, K2, DOSTAGE, ENDW)                                            \
    {                                                                                  \
        const char* bufc = (const char*)(BUF);                                         \
        bf16x8 fTi[4], fSi[4], fTj[2], fSj[2];                                         \
        /* ---- phase 0: read fTi,fTj | stage Ti(t+2) | mfma tt ---- */                \
        _Pragma("unroll")                                                              \
        for (int m = 0; m < 4; ++m)                                                    \
            fTi[m] = *reinterpret_cast<const bf16x8*>(bufc + aByte + m * 1024);        \
        _Pragma("unroll")                                                              \
        for (int n = 0; n < 2; ++n)                                                    \
            fTj[n] = *reinterpret_cast<const bf16x8*>(bufc + 8192 + bByte + n * 1024); \
        if (DOSTAGE) GLD16(Ti + gOff + (K2), (NBUF) + dOff);                           \
        SBAR; LGKM0; SCHED0;                                                           \
        __builtin_amdgcn_s_setprio(1);                                                 \
        MFMA8(att, fTi, fTj);                                                          \
        __builtin_amdgcn_s_setprio(0);                                                 \
        SBAR;                                                                          \
        /* ---- phase 1: read fSj | stage Tj(t+2) | mfma st ---- */                    \
        _Pragma("unroll")                                                              \
        for (int n = 0; n < 2; ++n)                                                    \
            fSj[n] = *reinterpret_cast<const bf16x8*>(bufc + 24576 + bByte + n * 1024);\
        if (DOSTAGE) GLD16(Tj + gOff + (K2), (NBUF) + 4096 + dOff);                    \
        SBAR; LGKM0; SCHED0;                                                           \
        __builtin_amdgcn_s_setprio(1);                                                 \
        MFMA8(ast, fTi, fSj);                                                          \
        __builtin_amdgcn_s_setprio(0);                                                 \
        SBAR;                                                                          \
        /* ---- phase 2: read fSi | stage Si(t+2) | mfma ts ---- */                    \
        _Pragma("unroll")                                                              \
        for (int m = 0; m < 4; ++m)                                                    \
            fSi[m] = *reinterpret_cast<const bf16x8*>(bufc + 16384 + aByte + m * 1024);\
        if (DOSTAGE) GLD16(Si + gOff + (K2), (NBUF) + 8192 + dOff);                    \
        SBAR; LGKM0; SCHED0;                                                           \
        __builtin_amdgcn_s_setprio(1);                                                 \
        MFMA8(ats, fSi, fTj);                                                          \
        __builtin_amdgcn_s_setprio(0);                                                 \
        SBAR;                                                                          \
        /* ---- phase 3: stage Sj(t+2) | mfma ss | end-of-step wait ---- */            \
        if (DOSTAGE) GLD16(Sj + gOff + (K2), (NBUF) + 12288 + dOff);                   \
        __builtin_amdgcn_s_setprio(1);                                                 \
        MFMA8(ass, fSi, fSj);                                                          \
        __builtin_amdgcn_s_setprio(0);                                                 \
        ENDW;                                                                          \
        SBAR; SCHED0;                                                                  \
    }

    for (int s = 0; s < KSTEPS - 2; ++s) {
        KSTEP(c0, c2, (s + 2) * 32, 1, WAITV4);
        unsigned short* tmp = c0; c0 = c1; c1 = c2; c2 = tmp;
    }
    KSTEP(c0, c2, 0, 0, WAITV0);
    { unsigned short* tmp = c0; c0 = c1; c1 = tmp; }
    KSTEP(c0, c2, 0, 0, (void)0);

    // ---- epilogue: weighted sum of squares (layout-free) ----
    float stt = 0.0f, sss = 0.0f, sst = 0.0f, sts = 0.0f;
#pragma unroll
    for (int m = 0; m < 4; ++m)
#pragma unroll
        for (int n = 0; n < 2; ++n)
#pragma unroll
            for (int q = 0; q < 4; ++q) {
                float x0 = att[m][n][q]; stt += x0 * x0;
                float x1 = ass[m][n][q]; sss += x1 * x1;
                float x2 = ast[m][n][q]; sst += x2 * x2;
                float x3 = ats[m][n][q]; sts += x3 * x3;
            }
    float v = wsym * (stt + sss) - 2.0f * wcross * (sst + sts);
#pragma unroll
    for (int m = 32; m >= 1; m >>= 1) v += __shfl_xor(v, m, 64);
    if (lane == 0) red[wid] = v;
    __syncthreads();
    if (tid == 0) {
        float tot = 0.0f;
#pragma unroll
        for (int q = 0; q < 8; ++q) tot += red[q];
        atomicAdd(&partials[0], tot);
    }
}

// ---------------------------------------------------------------------------
__global__ void finalize_kernel(const float* __restrict__ partials, float* __restrict__ out) {
    // mean over B*C*C = 64*512*512 = 16777216
    out[0] = partials[0] * (1.0f / 16777216.0f);
}

// ---------------------------------------------------------------------------
extern "C" void kernel_launch(void* const* d_in, const int* in_sizes, int n_in,
                              void* d_out, int out_size, void* d_ws, size_t ws_size,
                              hipStream_t stream) {
    const float* fs = (const float*)d_in[0];   // fm_s
    const float* ft = (const float*)d_in[1];   // fm_t
    float* out = (float*)d_out;

    char* ws = (char*)d_ws;
    float* partials = (float*)ws;                                  // 64 B
    unsigned short* Tn = (unsigned short*)(ws + 256);
    unsigned short* Sn = (unsigned short*)(ws + 256 + (size_t)B_ * C_ * LP * 2);
    // total ws use: 256 + 2*64*512*800*2 = ~104.9 MB

    hipLaunchKernelGGL(init_kernel, dim3(1), dim3(64), 0, stream, partials);
    hipLaunchKernelGGL(normalize_kernel, dim3(2048), dim3(256), 0, stream,
                       fs, ft, Tn, Sn);
    hipLaunchKernelGGL(gram_kernel, dim3(B_ * NPAIR), dim3(512), 0, stream,
                       Tn, Sn, partials);
    hipLaunchKernelGGL(finalize_kernel, dim3(1), dim3(1), 0, stream, partials, out);
}

// Round 10
// 122.595 us; speedup vs baseline: 1.0431x; 1.0431x over previous
//
#include <hip/hip_runtime.h>
#include <hip/hip_bf16.h>
#include <stdint.h>

// Problem geometry
#define B_   64
#define C_   512
#define L_   784      // 28*28
#define LP   800      // padded row length (25 * 32), pad is zero-filled
#define TILE 128
#define KSTEPS 25
#define NPAIR 10      // unordered tile pairs (i<=j) of 4 row-tiles
#define NXCD 8
#define NROWS 65536   // 2 * B_ * C_

#define AS1 __attribute__((address_space(1)))
#define AS3 __attribute__((address_space(3)))

typedef __attribute__((ext_vector_type(8))) __bf16 bf16x8;
typedef __attribute__((ext_vector_type(4))) float  f32x4;

#define WAITV4  asm volatile("s_waitcnt vmcnt(4)"  ::: "memory")
#define WAITV0  asm volatile("s_waitcnt vmcnt(0)"  ::: "memory")
#define LGKM0   asm volatile("s_waitcnt lgkmcnt(0)" ::: "memory")
#define SBAR    __builtin_amdgcn_s_barrier()
#define SCHED0  __builtin_amdgcn_sched_barrier(0)
#define GLD16(SRC, DST) __builtin_amdgcn_global_load_lds((AS1 const void*)(SRC), (AS3 void*)(DST), 16, 0, 0)

// ---------------------------------------------------------------------------
// round-to-nearest-even float -> bf16 bits (data has no NaN/Inf)
__device__ inline unsigned short f2bf(float x) {
    union { float f; uint32_t u; } a; a.f = x;
    uint32_t u = a.u;
    return (unsigned short)((u + 0x7fffu + ((u >> 16) & 1u)) >> 16);
}

// ---------------------------------------------------------------------------
// Pass 1 (v3): L2-normalize rows, fp32 -> bf16 padded to LP=800.
// 16 LANES PER ROW (4 rows/wave): 13 concurrent 16B loads per lane (13 KB
// in flight per wave, 3.2x v2), 4-level 16-lane shuffle reduce, near-zero
// tail divergence. Each 16-lane segment reads 256B contiguous.
// Also zeroes the partials accumulator (folded init).
__global__ __launch_bounds__(256) void normalize_kernel(
    const float* __restrict__ fs, const float* __restrict__ ft,
    unsigned short* __restrict__ outT, unsigned short* __restrict__ outS,
    float* __restrict__ partials)
{
    if (blockIdx.x == 0 && threadIdx.x < 16) partials[threadIdx.x] = 0.0f;

    int wid  = threadIdx.x >> 6;
    int lane = threadIdx.x & 63;
    int grp  = lane >> 4;                  // row within quad (0..3)
    int sub  = lane & 15;                  // lane within row
    int row  = (blockIdx.x * 4 + wid) * 4 + grp;   // 0..65535
    int mat  = row >> 15;                  // 0 -> t, 1 -> s
    int r    = row & 32767;

    const float* src = (mat == 0 ? ft : fs) + (size_t)r * L_;
    unsigned short* dst = (mat == 0 ? outT : outS) + (size_t)r * LP;

    // 784 floats = 196 float4 chunks; lane `sub` takes chunks it*16+sub
    float4 v[13];
#pragma unroll
    for (int it = 0; it < 12; ++it)
        v[it] = reinterpret_cast<const float4*>(src)[it * 16 + sub];
    if (sub < 4)  v[12] = reinterpret_cast<const float4*>(src)[192 + sub];
    else          v[12] = make_float4(0.f, 0.f, 0.f, 0.f);

    float ss = 0.0f;
#pragma unroll
    for (int it = 0; it < 13; ++it)
        ss += v[it].x * v[it].x + v[it].y * v[it].y
            + v[it].z * v[it].z + v[it].w * v[it].w;
    // reduce within the 16-lane group (xor masks stay inside the group)
#pragma unroll
    for (int m = 8; m >= 1; m >>= 1) ss += __shfl_xor(ss, m, 64);
    float rn = 1.0f / fmaxf(sqrtf(ss), 1e-12f);

#pragma unroll
    for (int it = 0; it < 12; ++it) {
        ushort4 o;
        o.x = f2bf(v[it].x * rn); o.y = f2bf(v[it].y * rn);
        o.z = f2bf(v[it].z * rn); o.w = f2bf(v[it].w * rn);
        *reinterpret_cast<ushort4*>(dst + (size_t)(it * 16 + sub) * 4) = o;
    }
    if (sub < 8) {                          // chunks 192..199: data + zero pad
        ushort4 o = make_ushort4(0, 0, 0, 0);
        if (sub < 4) {
            o.x = f2bf(v[12].x * rn); o.y = f2bf(v[12].y * rn);
            o.z = f2bf(v[12].z * rn); o.w = f2bf(v[12].w * rn);
        }
        *reinterpret_cast<ushort4*>(dst + (size_t)(192 + sub) * 4) = o;
    }
}

// ---------------------------------------------------------------------------
// Pass 2 (fused, 4-phase schedule): UNCHANGED from R8 (clean A/B vs normalize).
// One block per (batch, pair{i<=j}), full K. Stages panels T_i,T_j,S_i,S_j
// (8KB each) once per K-step; computes all four 128x128 products tt,st,ts,ss.
// 8 waves; wave w owns rows (w>>2)*64, cols (w&3)*32: 12 LDS frags -> 32 MFMA
// per step, 4 phases of {ds_read || 1 stage-GLD -> bar -> lgkm0 -> 8 MFMA ->
// bar}. Counted vmcnt(4) once per K-step; setprio; both-sides XOR swizzle;
// XCD block swizzle.
__global__ __launch_bounds__(512, 1) void gram_kernel(
    const unsigned short* __restrict__ Tn,
    const unsigned short* __restrict__ Sn,
    float* __restrict__ partials)
{
    // T1: bijective XCD chunk swizzle (640 = 8 XCDs x 80; 8 batches/XCD)
    int blk = (blockIdx.x % NXCD) * (B_ * NPAIR / NXCD) + blockIdx.x / NXCD;
    int b   = blk / NPAIR;
    int t   = blk % NPAIR;

    int i, j;
    if      (t < 4) { i = 0; j = t;     }
    else if (t < 7) { i = 1; j = t - 3; }
    else if (t < 9) { i = 2; j = t - 5; }
    else            { i = 3; j = 3;     }

    float wsym   = (i == j) ? 1.0f : 2.0f;
    float wcross = (i == j) ? 0.5f : 1.0f;

    const unsigned short* Ti = Tn + (size_t)b * C_ * LP + (size_t)i * TILE * LP;
    const unsigned short* Tj = Tn + (size_t)b * C_ * LP + (size_t)j * TILE * LP;
    const unsigned short* Si = Sn + (size_t)b * C_ * LP + (size_t)i * TILE * LP;
    const unsigned short* Sj = Sn + (size_t)b * C_ * LP + (size_t)j * TILE * LP;

    // 3 buffers x 32KB = 96KB; panel layout per buffer (shorts):
    // Ti@0, Tj@4096, Si@8192, Sj@12288
    __shared__ unsigned short lds[3 * 16384];
    __shared__ float red[8];

    int tid  = threadIdx.x;
    int wid  = tid >> 6;
    int lane = tid & 63;

    // staging addresses (T2 swizzle by pre-swizzled global source slot)
    int sr  = tid >> 2;                      // panel row 0..127
    int ssl = (tid & 3) ^ ((sr >> 1) & 3);   // swizzled 16B slot in row
    const size_t gOff = (size_t)sr * LP + ssl * 8;   // + k0 per step
    const int dOff = wid * 512;              // shorts; lane*16B implicit

    // fragment read addresses (swizzled read side, involution matches source)
    int rA = (wid >> 2) * 64 + (lane & 15);  // A-side panel row
    int rB = (wid & 3) * 32 + (lane & 15);   // B-side panel row
    int kb = (lane >> 4) * 16;               // 16B k-slot (bytes)
    int aByte = rA * 64 + (kb ^ (((rA >> 1) & 3) << 4));
    int bByte = rB * 64 + (kb ^ (((rB >> 1) & 3) << 4));

    f32x4 att[4][2] = {}, ast[4][2] = {}, ats[4][2] = {}, ass[4][2] = {};

    unsigned short* c0 = lds;
    unsigned short* c1 = lds + 16384;
    unsigned short* c2 = lds + 32768;

    // prologue: stage tiles 0,1 (8 GLD/thread outstanding)
    {
        GLD16(Ti + gOff, c0 + dOff);  GLD16(Tj + gOff, c0 + 4096 + dOff);
        GLD16(Si + gOff, c0 + 8192 + dOff);  GLD16(Sj + gOff, c0 + 12288 + dOff);
        GLD16(Ti + gOff + 32, c1 + dOff);  GLD16(Tj + gOff + 32, c1 + 4096 + dOff);
        GLD16(Si + gOff + 32, c1 + 8192 + dOff);  GLD16(Sj + gOff + 32, c1 + 12288 + dOff);
    }
    WAITV4;                 // tile 0 landed; tile 1's 4 loads in flight
    SBAR; SCHED0;

#define MFMA8(ACC, FA, FB)                                                             \
    _Pragma("unroll")                                                                  \
    for (int m = 0; m < 4; ++m)                                                        \
        _Pragma("unroll")                                                              \
        for (int n = 0; n < 2; ++n)                                                    \
            ACC[m][n] = __builtin_amdgcn_mfma_f32_16x16x32_bf16(FA[m], FB[n], ACC[m][n], 0, 0, 0);

#define KSTEP(BUF, NBUF, K2, DOSTAGE, ENDW)                                            \
    {                                                                                  \
        const char* bufc = (const char*)(BUF);                                         \
        bf16x8 fTi[4], fSi[4], fTj[2], fSj[2];                                         \
        /* ---- phase 0: read fTi,fTj | stage Ti(t+2) | mfma tt ---- */                \
        _Pragma("unroll")                                                              \
        for (int m = 0; m < 4; ++m)                                                    \
            fTi[m] = *reinterpret_cast<const bf16x8*>(bufc + aByte + m * 1024);        \
        _Pragma("unroll")                                                              \
        for (int n = 0; n < 2; ++n)                                                    \
            fTj[n] = *reinterpret_cast<const bf16x8*>(bufc + 8192 + bByte + n * 1024); \
        if (DOSTAGE) GLD16(Ti + gOff + (K2), (NBUF) + dOff);                           \
        SBAR; LGKM0; SCHED0;                                                           \
        __builtin_amdgcn_s_setprio(1);                                                 \
        MFMA8(att, fTi, fTj);                                                          \
        __builtin_amdgcn_s_setprio(0);                                                 \
        SBAR;                                                                          \
        /* ---- phase 1: read fSj | stage Tj(t+2) | mfma st ---- */                    \
        _Pragma("unroll")                                                              \
        for (int n = 0; n < 2; ++n)                                                    \
            fSj[n] = *reinterpret_cast<const bf16x8*>(bufc + 24576 + bByte + n * 1024);\
        if (DOSTAGE) GLD16(Tj + gOff + (K2), (NBUF) + 4096 + dOff);                    \
        SBAR; LGKM0; SCHED0;                                                           \
        __builtin_amdgcn_s_setprio(1);                                                 \
        MFMA8(ast, fTi, fSj);                                                          \
        __builtin_amdgcn_s_setprio(0);                                                 \
        SBAR;                                                                          \
        /* ---- phase 2: read fSi | stage Si(t+2) | mfma ts ---- */                    \
        _Pragma("unroll")                                                              \
        for (int m = 0; m < 4; ++m)                                                    \
            fSi[m] = *reinterpret_cast<const bf16x8*>(bufc + 16384 + aByte + m * 1024);\
        if (DOSTAGE) GLD16(Si + gOff + (K2), (NBUF) + 8192 + dOff);                    \
        SBAR; LGKM0; SCHED0;                                                           \
        __builtin_amdgcn_s_setprio(1);                                                 \
        MFMA8(ats, fSi, fTj);                                                          \
        __builtin_amdgcn_s_setprio(0);                                                 \
        SBAR;                                                                          \
        /* ---- phase 3: stage Sj(t+2) | mfma ss | end-of-step wait ---- */            \
        if (DOSTAGE) GLD16(Sj + gOff + (K2), (NBUF) + 12288 + dOff);                   \
        __builtin_amdgcn_s_setprio(1);                                                 \
        MFMA8(ass, fSi, fSj);                                                          \
        __builtin_amdgcn_s_setprio(0);                                                 \
        ENDW;                                                                          \
        SBAR; SCHED0;                                                                  \
    }

    for (int s = 0; s < KSTEPS - 2; ++s) {
        KSTEP(c0, c2, (s + 2) * 32, 1, WAITV4);
        unsigned short* tmp = c0; c0 = c1; c1 = c2; c2 = tmp;
    }
    KSTEP(c0, c2, 0, 0, WAITV0);
    { unsigned short* tmp = c0; c0 = c1; c1 = tmp; }
    KSTEP(c0, c2, 0, 0, (void)0);

    // ---- epilogue: weighted sum of squares (layout-free) ----
    float stt = 0.0f, sss = 0.0f, sst = 0.0f, sts = 0.0f;
#pragma unroll
    for (int m = 0; m < 4; ++m)
#pragma unroll
        for (int n = 0; n < 2; ++n)
#pragma unroll
            for (int q = 0; q < 4; ++q) {
                float x0 = att[m][n][q]; stt += x0 * x0;
                float x1 = ass[m][n][q]; sss += x1 * x1;
                float x2 = ast[m][n][q]; sst += x2 * x2;
                float x3 = ats[m][n][q]; sts += x3 * x3;
            }
    float v = wsym * (stt + sss) - 2.0f * wcross * (sst + sts);
#pragma unroll
    for (int m = 32; m >= 1; m >>= 1) v += __shfl_xor(v, m, 64);
    if (lane == 0) red[wid] = v;
    __syncthreads();
    if (tid == 0) {
        float tot = 0.0f;
#pragma unroll
        for (int q = 0; q < 8; ++q) tot += red[q];
        atomicAdd(&partials[0], tot);
    }
}

// ---------------------------------------------------------------------------
__global__ void finalize_kernel(const float* __restrict__ partials, float* __restrict__ out) {
    // mean over B*C*C = 64*512*512 = 16777216
    out[0] = partials[0] * (1.0f / 16777216.0f);
}

// ---------------------------------------------------------------------------
extern "C" void kernel_launch(void* const* d_in, const int* in_sizes, int n_in,
                              void* d_out, int out_size, void* d_ws, size_t ws_size,
                              hipStream_t stream) {
    const float* fs = (const float*)d_in[0];   // fm_s
    const float* ft = (const float*)d_in[1];   // fm_t
    float* out = (float*)d_out;

    char* ws = (char*)d_ws;
    float* partials = (float*)ws;                                  // 64 B
    unsigned short* Tn = (unsigned short*)(ws + 256);
    unsigned short* Sn = (unsigned short*)(ws + 256 + (size_t)B_ * C_ * LP * 2);
    // total ws use: 256 + 2*64*512*800*2 = ~104.9 MB

    hipLaunchKernelGGL(normalize_kernel, dim3(NROWS / 16), dim3(256), 0, stream,
                       fs, ft, Tn, Sn, partials);
    hipLaunchKernelGGL(gram_kernel, dim3(B_ * NPAIR), dim3(512), 0, stream,
                       Tn, Sn, partials);
    hipLaunchKernelGGL(finalize_kernel, dim3(1), dim3(1), 0, stream, partials, out);
}